// Round 1
// 115.451 us; speedup vs baseline: 1.0478x; 1.0478x over previous
//
#include <hip/hip_runtime.h>
#include <stdint.h>

// Problem geometry (fixed by setup_inputs)
#define HW    1024
#define BATCH 32
#define TR    16                 // rows per block tile
#define HR    (TR + 6)           // tile rows + 3-row halo each side
#define WN    32                 // u32 words per row (bit = col)
#define TILES (HW / TR)          // 64 tiles per image
#define NBLK  (BATCH * TILES)    // 2048 blocks in kernel 1

// weight constants: 1 - tanh(d/3) for d = 1,2,3
#define W1 0.6784872f
#define W2 0.4172171f
#define W3 0.2384058f

__global__ __launch_bounds__(256) void k_main(const float* __restrict__ pred,
                                              const float* __restrict__ targ,
                                              float* __restrict__ ws) {
    // raw foreground bits (bit i of word w = col 32w+i); zero outside image
    __shared__ uint32_t fg[HR][WN];
    // horizontal bit-spans (cols +-1/2/3) for fg and bg
    __shared__ uint32_t h1f[HR][WN], h2f[HR][WN], h3f[HR][WN];
    __shared__ uint32_t h1b[HR][WN], h2b[HR][WN], h3b[HR][WN];
    // packed per-word planes: {t, dil1(opp), dil2(opp), dil3(opp)} selected per bit
    __shared__ uint4 plane[TR][WN];
    __shared__ float red[4][8];

    const int blk  = blockIdx.x;
    const int b    = blk / TILES;
    const int tile = blk - b * TILES;
    const int r0   = tile * TR;
    const int tid  = threadIdx.x;
    const int lane = tid & 63;
    const int wid  = tid >> 6;

    // zero fg (halo rows outside the image stay zero)
    for (int i = tid; i < HR * WN; i += 256) (&fg[0][0])[i] = 0u;
    __syncthreads();

    // ---- phase A: build fg bitmasks via wave ballots (targets are exactly 0/1)
    const float* tbase = targ + (size_t)b * HW * HW;
    for (int task = wid; task < HR * 16; task += 4) {
        const int row = task >> 4;       // 0..HR-1  (uniform per wave)
        const int g   = task & 15;       // 64-col group
        const int gr  = r0 - 3 + row;
        if (gr >= 0 && gr < HW) {
            float tv = tbase[(size_t)gr * HW + (g << 6) + lane];
            unsigned long long m = __ballot(tv > 0.5f);
            if (lane == 0) {
                fg[row][2 * g]     = (uint32_t)m;
                fg[row][2 * g + 1] = (uint32_t)(m >> 32);
            }
        }
    }
    __syncthreads();

    // ---- phase B1: horizontal spans per word (word-parallel, amortized over 32 px)
    for (int i = tid; i < HR * WN; i += 256) {
        const int row = i >> 5;
        const int wz  = i & 31;
        const int gr  = r0 - 3 + row;
        const bool valid = (gr >= 0) && (gr < HW);
        const uint32_t cur = fg[row][wz];
        const uint32_t prv = (wz > 0)  ? fg[row][wz - 1] : 0u;
        const uint32_t nxt = (wz < 31) ? fg[row][wz + 1] : 0u;

        uint32_t s1 = cur | (cur << 1) | (prv >> 31) | (cur >> 1) | (nxt << 31);
        uint32_t s2 = s1  | (cur << 2) | (prv >> 30) | (cur >> 2) | (nxt << 30);
        uint32_t s3 = s2  | (cur << 3) | (prv >> 29) | (cur >> 3) | (nxt << 29);
        h1f[row][wz] = s1; h2f[row][wz] = s2; h3f[row][wz] = s3;

        // background = complement inside the image only (SAME padding = empty)
        const uint32_t cb = valid ? ~cur : 0u;
        const uint32_t pb = (valid && wz > 0)  ? ~prv : 0u;
        const uint32_t nb = (valid && wz < 31) ? ~nxt : 0u;
        uint32_t t1 = cb | (cb << 1) | (pb >> 31) | (cb >> 1) | (nb << 31);
        uint32_t t2 = t1 | (cb << 2) | (pb >> 30) | (cb >> 2) | (nb << 30);
        uint32_t t3 = t2 | (cb << 3) | (pb >> 29) | (cb >> 3) | (nb << 29);
        h1b[row][wz] = t1; h2b[row][wz] = t2; h3b[row][wz] = t3;
    }
    __syncthreads();

    // ---- phase B2: vertical ORs -> nested dilations; per-bit fg/bg select (bfi)
    for (int i = tid; i < TR * WN; i += 256) {
        const int row = i >> 5;
        const int wz  = i & 31;
        const int hr  = row + 3;
        const uint32_t t = fg[hr][wz];
        uint32_t d1f = h1f[hr-1][wz] | h1f[hr][wz] | h1f[hr+1][wz];
        uint32_t d2f = h2f[hr-2][wz] | h2f[hr-1][wz] | h2f[hr][wz]
                     | h2f[hr+1][wz] | h2f[hr+2][wz];
        uint32_t d3f = h3f[hr-3][wz] | h3f[hr-2][wz] | h3f[hr-1][wz] | h3f[hr][wz]
                     | h3f[hr+1][wz] | h3f[hr+2][wz] | h3f[hr+3][wz];
        uint32_t d1b = h1b[hr-1][wz] | h1b[hr][wz] | h1b[hr+1][wz];
        uint32_t d2b = h2b[hr-2][wz] | h2b[hr-1][wz] | h2b[hr][wz]
                     | h2b[hr+1][wz] | h2b[hr+2][wz];
        uint32_t d3b = h3b[hr-3][wz] | h3b[hr-2][wz] | h3b[hr-1][wz] | h3b[hr][wz]
                     | h3b[hr+1][wz] | h3b[hr+2][wz] | h3b[hr+3][wz];
        uint4 pl;
        pl.x = t;                                  // target bits
        pl.y = (t & d1b) | (~t & d1f);             // dist<=1 to opposite class
        pl.z = (t & d2b) | (~t & d2f);             // dist<=2
        pl.w = (t & d3b) | (~t & d3f);             // dist<=3  (nested: y<=z<=w)
        plane[row][wz] = pl;
    }
    __syncthreads();

    // ---- phase C: per-pixel math; one row per iteration, float4 per thread
    float s_pt = 0.f, s_p = 0.f, s_t = 0.f, s_w = 0.f, s_bw = 0.f, s_ce = 0.f, s_f = 0.f;
    const float4* p4 = (const float4*)(pred + (size_t)b * HW * HW + (size_t)r0 * HW);
    const int wz = tid >> 3;             // word index for cols tid*4..tid*4+3
    const int sh = (tid & 7) << 2;       // nibble shift within the word

    float4 x4 = p4[tid];
    for (int rr = 0; rr < TR; ++rr) {
        const float4 cur = x4;
        if (rr + 1 < TR) x4 = p4[(rr + 1) * 256 + tid];
        const uint4 pl = plane[rr][wz];  // broadcast b128 read, conflict-free
        const uint32_t tn = (pl.x >> sh) & 0xFu;
        const uint32_t n1 = (pl.y >> sh) & 0xFu;
        const uint32_t n2 = (pl.z >> sh) & 0xFu;
        const uint32_t n3 = (pl.w >> sh) & 0xFu;
#pragma unroll
        for (int j = 0; j < 4; ++j) {
            const float x = ((const float*)&cur)[j];
            const uint32_t tb = (tn >> j) & 1u;
            const float tf = (float)tb;

            const float ax  = fabsf(x);
            const float e   = __expf(-ax);                 // exp(-|x|) in (0,1]
            const float opl = 1.f + e;
            const float inv = __builtin_amdgcn_rcpf(opl);  // sigmoid(|x|), 1 ulp
            const float l1p = __logf(opl);                 // log1p(exp(-|x|))
            const float ce  = fmaxf(x, 0.f) - x * tf + l1p;
            const float pm  = 1.f - inv;
            const float p   = (x >= 0.f) ? inv : pm;       // sigmoid(x)
            const float omp = tb ? (1.f - p) : p;          // 1 - p_t
            const float at  = tb ? 0.25f : 0.75f;
            const float fo  = ce * omp * omp * at;

            // nested bits -> weight: n = b1+b2+b3, w = [0,W3,W2,W1][n]
            const float f1 = (float)((n1 >> j) & 1u);
            const float f2 = (float)((n2 >> j) & 1u);
            const float f3 = (float)((n3 >> j) & 1u);
            const float w  = fmaf(f1, W1 - W2, fmaf(f2, W2 - W3, f3 * W3));

            s_ce += ce;
            s_f  += fo;
            s_p  += p;
            s_pt  = fmaf(tf, p, s_pt);
            s_t  += tf;
            s_w  += w;
            s_bw  = fmaf(w, ce, s_bw);
        }
    }

    // deterministic block reduction: wave shuffle tree, then 4-wave combine
    float v[7] = {s_pt, s_p, s_t, s_w, s_bw, s_ce, s_f};
#pragma unroll
    for (int off = 1; off < 64; off <<= 1) {
#pragma unroll
        for (int j = 0; j < 7; ++j) v[j] += __shfl_xor(v[j], off);
    }
    if (lane == 0) {
#pragma unroll
        for (int j = 0; j < 7; ++j) red[wid][j] = v[j];
    }
    __syncthreads();
    if (tid < 7) {
        float s = red[0][tid] + red[1][tid] + red[2][tid] + red[3][tid];
        ws[tid * NBLK + blk] = s;
    }
}

// per-batch deterministic tree reduction over the 64 tile partials
__global__ __launch_bounds__(TILES) void k_reduce(const float* __restrict__ ws,
                                                  float* __restrict__ res) {
    __shared__ float sm[TILES];
    const int b = blockIdx.x;
    const int t = threadIdx.x;
    for (int q = 0; q < 7; ++q) {
        sm[t] = ws[q * NBLK + b * TILES + t];
        __syncthreads();
        for (int s = TILES / 2; s > 0; s >>= 1) {
            if (t < s) sm[t] += sm[t + s];
            __syncthreads();
        }
        if (t == 0) res[q * BATCH + b] = sm[0];
        __syncthreads();
    }
}

__global__ __launch_bounds__(64) void k_final(const float* __restrict__ res,
                                              const float* __restrict__ lv,
                                              float* __restrict__ out) {
    const int lane = threadIdx.x;
    float d = 0.f, io = 0.f, bn = 0.f;
    if (lane < 32) {
        const float pt = res[0 * 32 + lane];
        const float p  = res[1 * 32 + lane];
        const float t  = res[2 * 32 + lane];
        const float w  = res[3 * 32 + lane];
        const float bw = res[4 * 32 + lane];
        d  = 1.f - (2.f * pt + 1.f) / (p + t + 1.f);
        io = 1.f - (pt + 1e-6f) / (p + t - pt + 1e-6f);
        bn = bw / fmaxf(w, 1.f);
    }
#pragma unroll
    for (int off = 1; off < 32; off <<= 1) {
        d  += __shfl_xor(d, off);
        io += __shfl_xor(io, off);
        bn += __shfl_xor(bn, off);
    }
    if (lane == 0) {
        float ce_sum = 0.f, f_sum = 0.f;
        for (int bb = 0; bb < 32; ++bb) {
            ce_sum += res[5 * 32 + bb];
            f_sum  += res[6 * 32 + bb];
        }
        const float N = 33554432.f;   // 32*1024*1024
        float ls[5];
        ls[0] = ce_sum / N;                    // ce
        ls[1] = d * (1.f / 32.f);              // dice
        ls[2] = 0.5f * f_sum / N;              // focal
        ls[3] = 0.3f * io * (1.f / 32.f);      // iou
        ls[4] = 0.2f * bn * (1.f / 32.f);      // boundary
        float r[5], s = 0.f;
#pragma unroll
        for (int i = 0; i < 5; ++i) {
            r[i] = 1.f / (1.f + __expf(-lv[i] * (1.f / 1.5f)));
            s += r[i];
        }
        float tot = 0.f;
#pragma unroll
        for (int i = 0; i < 5; ++i) tot += (r[i] / s) * 5.f * ls[i];
        out[0] = tot;
    }
}

extern "C" void kernel_launch(void* const* d_in, const int* in_sizes, int n_in,
                              void* d_out, int out_size, void* d_ws, size_t ws_size,
                              hipStream_t stream) {
    const float* pred = (const float*)d_in[0];
    const float* targ = (const float*)d_in[1];
    const float* lv   = (const float*)d_in[2];
    float* out = (float*)d_out;
    float* ws  = (float*)d_ws;                 // [7][NBLK] partials
    float* res = ws + 7 * NBLK;                // [7][BATCH] per-batch sums

    k_main<<<NBLK, 256, 0, stream>>>(pred, targ, ws);
    k_reduce<<<BATCH, TILES, 0, stream>>>(ws, res);
    k_final<<<1, 64, 0, stream>>>(res, lv, out);
}

// Round 2
// 81.407 us; speedup vs baseline: 1.4860x; 1.4182x over previous
//
#include <hip/hip_runtime.h>
#include <stdint.h>

// Problem geometry (fixed by setup_inputs)
#define HW    1024
#define BATCH 32
#define TR    16                 // rows per block tile
#define HR    (TR + 6)           // tile rows + 3-row halo each side
#define WN    32                 // u32 words per row (bit = col)
#define TILES (HW / TR)          // 64 tiles per image
#define NBLK  (BATCH * TILES)    // 2048 blocks in kernel 1

// weight constants: 1 - tanh(d/3) for d = 1,2,3
#define W1 0.6784872f
#define W2 0.4172171f
#define W3 0.2384058f

__global__ __launch_bounds__(256) void k_main(const float* __restrict__ pred,
                                              const float* __restrict__ targ,
                                              float* __restrict__ ws) {
    // raw foreground bits (bit i of word w = col 32w+i); zero outside image
    __shared__ uint32_t fg[HR][WN];
    // packed per-word planes: {t, dil1(opp), dil2(opp), dil3(opp)} selected per bit
    __shared__ uint4 plane[TR][WN];
    __shared__ float red[4][8];
    // total LDS: 2816 + 8192 + 128 = 11136 B  -> 8 blocks/CU co-resident

    const int bid  = blockIdx.x;
    // XCD-contiguous swizzle: all 64 tiles of an image on one XCD (halo L2 reuse)
    const int blk  = (bid & 7) * (NBLK / 8) + (bid >> 3);
    const int b    = blk / TILES;
    const int tile = blk - b * TILES;
    const int r0   = tile * TR;
    const int tid  = threadIdx.x;
    const int lane = tid & 63;
    const int wid  = tid >> 6;

    // early pred prefetch: these loads ride in flight across phases A and B
    const float4* p4 = (const float4*)(pred + (size_t)b * HW * HW + (size_t)r0 * HW);
    float4 xa = p4[tid];
    float4 xb = p4[256 + tid];

    // zero fg (halo rows outside the image stay zero)
    for (int i = tid; i < HR * WN; i += 256) (&fg[0][0])[i] = 0u;
    __syncthreads();

    // ---- phase A: float4 targ loads; 4 bits/lane; 8-lane OR-combine -> one word
    const float* tbase = targ + (size_t)b * HW * HW;
    for (int task = wid; task < HR * 4; task += 4) {
        const int row = task >> 2;       // 0..HR-1  (uniform per wave)
        const int g   = task & 3;        // 256-col group
        const int gr  = r0 - 3 + row;
        if (gr >= 0 && gr < HW) {
            const float4 t4 = *(const float4*)(tbase + (size_t)gr * HW + (g << 8) + (lane << 2));
            // targets are exactly 0.0f / 1.0f -> bit 23 of the float pattern
            const uint32_t u0 = __float_as_uint(t4.x), u1 = __float_as_uint(t4.y);
            const uint32_t u2 = __float_as_uint(t4.z), u3 = __float_as_uint(t4.w);
            const uint32_t n = ((u0 >> 23) & 1u) | ((u1 >> 22) & 2u)
                             | ((u2 >> 21) & 4u) | ((u3 >> 20) & 8u);
            uint32_t v = n << ((lane & 7) << 2);
            v |= __shfl_xor(v, 1);
            v |= __shfl_xor(v, 2);
            v |= __shfl_xor(v, 4);
            if ((lane & 7) == 0) fg[row][(g << 3) + (lane >> 3)] = v;
        }
    }
    __syncthreads();

    // ---- phase B: plane directly from fg, vertical-first separable box-OR
    for (int i = tid; i < TR * WN; i += 256) {
        const int row = i >> 5;
        const int wz  = i & 31;
        const int hr  = row + 3;
        uint32_t v1c = 0, v2c = 0, v3c = 0, v1p = 0, v2p = 0, v3p = 0, v1n = 0, v2n = 0, v3n = 0;
        uint32_t u1c = 0, u2c = 0, u3c = 0, u1p = 0, u2p = 0, u3p = 0, u1n = 0, u2n = 0, u3n = 0;
        uint32_t tw = 0;
#pragma unroll
        for (int dr = -3; dr <= 3; ++dr) {
            const int r  = hr + dr;
            const int gr = r0 - 3 + r;
            const bool valid = (gr >= 0) && (gr < HW);
            const uint32_t c = fg[r][wz];
            const uint32_t p = (wz > 0)  ? fg[r][wz - 1] : 0u;
            const uint32_t n = (wz < 31) ? fg[r][wz + 1] : 0u;
            // background = complement inside the image only (SAME padding = empty)
            const uint32_t cb = valid ? ~c : 0u;
            const uint32_t pb = (valid && wz > 0)  ? ~p : 0u;
            const uint32_t nb = (valid && wz < 31) ? ~n : 0u;
            if (dr == 0) tw = c;
            v3c |= c;  v3p |= p;  v3n |= n;
            u3c |= cb; u3p |= pb; u3n |= nb;
            if (dr >= -2 && dr <= 2) {
                v2c |= c;  v2p |= p;  v2n |= n;
                u2c |= cb; u2p |= pb; u2n |= nb;
            }
            if (dr >= -1 && dr <= 1) {
                v1c |= c;  v1p |= p;  v1n |= n;
                u1c |= cb; u1p |= pb; u1n |= nb;
            }
        }
        const uint32_t d1f = v1c | (v1c << 1) | (v1p >> 31) | (v1c >> 1) | (v1n << 31);
        const uint32_t d2f = v2c | (v2c << 1) | (v2p >> 31) | (v2c >> 1) | (v2n << 31)
                                 | (v2c << 2) | (v2p >> 30) | (v2c >> 2) | (v2n << 30);
        const uint32_t d3f = v3c | (v3c << 1) | (v3p >> 31) | (v3c >> 1) | (v3n << 31)
                                 | (v3c << 2) | (v3p >> 30) | (v3c >> 2) | (v3n << 30)
                                 | (v3c << 3) | (v3p >> 29) | (v3c >> 3) | (v3n << 29);
        const uint32_t d1b = u1c | (u1c << 1) | (u1p >> 31) | (u1c >> 1) | (u1n << 31);
        const uint32_t d2b = u2c | (u2c << 1) | (u2p >> 31) | (u2c >> 1) | (u2n << 31)
                                 | (u2c << 2) | (u2p >> 30) | (u2c >> 2) | (u2n << 30);
        const uint32_t d3b = u3c | (u3c << 1) | (u3p >> 31) | (u3c >> 1) | (u3n << 31)
                                 | (u3c << 2) | (u3p >> 30) | (u3c >> 2) | (u3n << 30)
                                 | (u3c << 3) | (u3p >> 29) | (u3c >> 3) | (u3n << 29);
        uint4 pl;
        pl.x = tw;                                  // target bits
        pl.y = (tw & d1b) | (~tw & d1f);            // dist<=1 to opposite class
        pl.z = (tw & d2b) | (~tw & d2f);            // dist<=2
        pl.w = (tw & d3b) | (~tw & d3f);            // dist<=3  (nested)
        plane[row][wz] = pl;
    }
    __syncthreads();

    // ---- phase C: per-pixel math; one row per iteration, float4/thread, depth-2 prefetch
    float s_pt = 0.f, s_p = 0.f, s_t = 0.f, s_w = 0.f, s_bw = 0.f, s_ce = 0.f, s_f = 0.f;
    const int wz = tid >> 3;             // word index for cols tid*4..tid*4+3
    const int sh = (tid & 7) << 2;       // nibble shift within the word

    for (int rr = 0; rr < TR; ++rr) {
        const float4 cur = xa;
        xa = xb;
        if (rr + 2 < TR) xb = p4[(rr + 2) * 256 + tid];
        const uint4 pl = plane[rr][wz];  // broadcast b128 read, conflict-free
        const uint32_t tn = (pl.x >> sh) & 0xFu;
        const uint32_t n1 = (pl.y >> sh) & 0xFu;
        const uint32_t n2 = (pl.z >> sh) & 0xFu;
        const uint32_t n3 = (pl.w >> sh) & 0xFu;
#pragma unroll
        for (int j = 0; j < 4; ++j) {
            const float x = ((const float*)&cur)[j];
            const uint32_t tb = (tn >> j) & 1u;
            const float tf = (float)tb;

            const float ax  = fabsf(x);
            const float e   = __expf(-ax);                 // exp(-|x|) in (0,1]
            const float opl = 1.f + e;
            const float inv = __builtin_amdgcn_rcpf(opl);  // sigmoid(|x|), 1 ulp
            const float l1p = __logf(opl);                 // log1p(exp(-|x|))
            const float ce  = fmaxf(x, 0.f) - x * tf + l1p;
            const float pm  = 1.f - inv;
            const float p   = (x >= 0.f) ? inv : pm;       // sigmoid(x)
            const float omp = tb ? (1.f - p) : p;          // 1 - p_t
            const float at  = tb ? 0.25f : 0.75f;
            const float fo  = ce * omp * omp * at;

            // nested bits -> weight: w = f1*(W1-W2) + f2*(W2-W3) + f3*W3
            const float f1 = (float)((n1 >> j) & 1u);
            const float f2 = (float)((n2 >> j) & 1u);
            const float f3 = (float)((n3 >> j) & 1u);
            const float w  = fmaf(f1, W1 - W2, fmaf(f2, W2 - W3, f3 * W3));

            s_ce += ce;
            s_f  += fo;
            s_p  += p;
            s_pt  = fmaf(tf, p, s_pt);
            s_t  += tf;
            s_w  += w;
            s_bw  = fmaf(w, ce, s_bw);
        }
    }

    // deterministic block reduction: wave shuffle tree, then 4-wave combine
    float v[7] = {s_pt, s_p, s_t, s_w, s_bw, s_ce, s_f};
#pragma unroll
    for (int off = 1; off < 64; off <<= 1) {
#pragma unroll
        for (int j = 0; j < 7; ++j) v[j] += __shfl_xor(v[j], off);
    }
    if (lane == 0) {
#pragma unroll
        for (int j = 0; j < 7; ++j) red[wid][j] = v[j];
    }
    __syncthreads();
    if (tid < 7) {
        float s = red[0][tid] + red[1][tid] + red[2][tid] + red[3][tid];
        ws[tid * NBLK + blk] = s;
    }
}

// per-batch deterministic tree reduction over the 64 tile partials
__global__ __launch_bounds__(TILES) void k_reduce(const float* __restrict__ ws,
                                                  float* __restrict__ res) {
    __shared__ float sm[TILES];
    const int b = blockIdx.x;
    const int t = threadIdx.x;
    for (int q = 0; q < 7; ++q) {
        sm[t] = ws[q * NBLK + b * TILES + t];
        __syncthreads();
        for (int s = TILES / 2; s > 0; s >>= 1) {
            if (t < s) sm[t] += sm[t + s];
            __syncthreads();
        }
        if (t == 0) res[q * BATCH + b] = sm[0];
        __syncthreads();
    }
}

__global__ __launch_bounds__(64) void k_final(const float* __restrict__ res,
                                              const float* __restrict__ lv,
                                              float* __restrict__ out) {
    const int lane = threadIdx.x;
    float d = 0.f, io = 0.f, bn = 0.f;
    if (lane < 32) {
        const float pt = res[0 * 32 + lane];
        const float p  = res[1 * 32 + lane];
        const float t  = res[2 * 32 + lane];
        const float w  = res[3 * 32 + lane];
        const float bw = res[4 * 32 + lane];
        d  = 1.f - (2.f * pt + 1.f) / (p + t + 1.f);
        io = 1.f - (pt + 1e-6f) / (p + t - pt + 1e-6f);
        bn = bw / fmaxf(w, 1.f);
    }
#pragma unroll
    for (int off = 1; off < 32; off <<= 1) {
        d  += __shfl_xor(d, off);
        io += __shfl_xor(io, off);
        bn += __shfl_xor(bn, off);
    }
    if (lane == 0) {
        float ce_sum = 0.f, f_sum = 0.f;
        for (int bb = 0; bb < 32; ++bb) {
            ce_sum += res[5 * 32 + bb];
            f_sum  += res[6 * 32 + bb];
        }
        const float N = 33554432.f;   // 32*1024*1024
        float ls[5];
        ls[0] = ce_sum / N;                    // ce
        ls[1] = d * (1.f / 32.f);              // dice
        ls[2] = 0.5f * f_sum / N;              // focal
        ls[3] = 0.3f * io * (1.f / 32.f);      // iou
        ls[4] = 0.2f * bn * (1.f / 32.f);      // boundary
        float r[5], s = 0.f;
#pragma unroll
        for (int i = 0; i < 5; ++i) {
            r[i] = 1.f / (1.f + __expf(-lv[i] * (1.f / 1.5f)));
            s += r[i];
        }
        float tot = 0.f;
#pragma unroll
        for (int i = 0; i < 5; ++i) tot += (r[i] / s) * 5.f * ls[i];
        out[0] = tot;
    }
}

extern "C" void kernel_launch(void* const* d_in, const int* in_sizes, int n_in,
                              void* d_out, int out_size, void* d_ws, size_t ws_size,
                              hipStream_t stream) {
    const float* pred = (const float*)d_in[0];
    const float* targ = (const float*)d_in[1];
    const float* lv   = (const float*)d_in[2];
    float* out = (float*)d_out;
    float* ws  = (float*)d_ws;                 // [7][NBLK] partials
    float* res = ws + 7 * NBLK;                // [7][BATCH] per-batch sums

    k_main<<<NBLK, 256, 0, stream>>>(pred, targ, ws);
    k_reduce<<<BATCH, TILES, 0, stream>>>(ws, res);
    k_final<<<1, 64, 0, stream>>>(res, lv, out);
}

// Round 4
// 76.128 us; speedup vs baseline: 1.5890x; 1.0693x over previous
//
#include <hip/hip_runtime.h>
#include <stdint.h>

// Problem geometry (fixed by setup_inputs)
#define HW    1024
#define BATCH 32
#define TR    16                 // rows per block tile
#define HR    (TR + 6)           // tile rows + 3-row halo each side
#define WN    32                 // u32 words per row (bit = col)
#define TILES (HW / TR)          // 64 tiles per image
#define NBLK  (BATCH * TILES)    // 2048 blocks in kernel 1

// weight constants: 1 - tanh(d/3) for d = 1,2,3
#define W1 0.6784872f
#define W2 0.4172171f
#define W3 0.2384058f

typedef float v2f __attribute__((ext_vector_type(2)));

static __device__ __forceinline__ v2f pk_fma(v2f a, v2f b, v2f c) {
    return __builtin_elementwise_fma(a, b, c);
}

__global__ __launch_bounds__(256) void k_main(const float* __restrict__ pred,
                                              const float* __restrict__ targ,
                                              float* __restrict__ ws) {
    // raw foreground bits (bit i of word w = col 32w+i); halo rows outside image = 0
    __shared__ uint32_t fg[HR][WN];
    // packed per-word planes: {t, dil1(opp), dil2(opp), dil3(opp)} selected per bit
    __shared__ uint4 plane[TR][WN];
    __shared__ float red[4][8];
    // total LDS: 2816 + 8192 + 128 = 11136 B  -> 8 blocks/CU co-resident

    const int bid  = blockIdx.x;
    // XCD-contiguous swizzle: all 64 tiles of an image on one XCD (halo L2 reuse)
    const int blk  = (bid & 7) * (NBLK / 8) + (bid >> 3);
    const int b    = blk / TILES;
    const int tile = blk - b * TILES;
    const int r0   = tile * TR;
    const int tid  = threadIdx.x;
    const int lane = tid & 63;
    const int wid  = tid >> 6;

    // early pred prefetch: these loads ride in flight across phases A and B
    const float4* p4 = (const float4*)(pred + (size_t)b * HW * HW + (size_t)r0 * HW);
    float4 xa = p4[tid];
    float4 xb = p4[256 + tid];

    // ---- phase A: float4 targ loads; 4 bits/lane; 8-lane OR-combine -> one word
    // (writes ALL rows incl. zeros for out-of-image halo -> no pre-zero pass needed)
    const float* tbase = targ + (size_t)b * HW * HW;
    for (int task = wid; task < HR * 4; task += 4) {
        const int row = task >> 2;       // 0..HR-1  (uniform per wave)
        const int g   = task & 3;        // 256-col group
        const int gr  = r0 - 3 + row;
        uint32_t v = 0u;
        if (gr >= 0 && gr < HW) {        // wave-uniform branch
            const float4 t4 = *(const float4*)(tbase + (size_t)gr * HW + (g << 8) + (lane << 2));
            // targets are exactly 0.0f / 1.0f -> bit 23 of the float pattern
            const uint32_t u0 = __float_as_uint(t4.x), u1 = __float_as_uint(t4.y);
            const uint32_t u2 = __float_as_uint(t4.z), u3 = __float_as_uint(t4.w);
            const uint32_t n = ((u0 >> 23) & 1u) | ((u1 >> 22) & 2u)
                             | ((u2 >> 21) & 4u) | ((u3 >> 20) & 8u);
            v = n << ((lane & 7) << 2);
        }
        v |= __shfl_xor(v, 1);
        v |= __shfl_xor(v, 2);
        v |= __shfl_xor(v, 4);
        if ((lane & 7) == 0) fg[row][(g << 3) + (lane >> 3)] = v;
    }
    __syncthreads();

    // ---- phase B: plane directly from fg, vertical-first separable box-OR.
    // Also: word-parallel popcounts give sum(t) and sum(w) exactly (hoisted
    // out of the per-pixel loop).
    uint32_t ct = 0, c1 = 0, c2 = 0, c3 = 0;
    for (int i = tid; i < TR * WN; i += 256) {
        const int row = i >> 5;
        const int wz  = i & 31;
        const int hr  = row + 3;
        uint32_t v1c = 0, v2c = 0, v3c = 0, v1p = 0, v2p = 0, v3p = 0, v1n = 0, v2n = 0, v3n = 0;
        uint32_t u1c = 0, u2c = 0, u3c = 0, u1p = 0, u2p = 0, u3p = 0, u1n = 0, u2n = 0, u3n = 0;
        uint32_t tw = 0;
#pragma unroll
        for (int dr = -3; dr <= 3; ++dr) {
            const int r  = hr + dr;
            const int gr = r0 - 3 + r;
            const bool valid = (gr >= 0) && (gr < HW);
            const uint32_t c = fg[r][wz];
            const uint32_t p = (wz > 0)  ? fg[r][wz - 1] : 0u;
            const uint32_t n = (wz < 31) ? fg[r][wz + 1] : 0u;
            // background = complement inside the image only (SAME padding = empty)
            const uint32_t cb = valid ? ~c : 0u;
            const uint32_t pb = (valid && wz > 0)  ? ~p : 0u;
            const uint32_t nb = (valid && wz < 31) ? ~n : 0u;
            if (dr == 0) tw = c;
            v3c |= c;  v3p |= p;  v3n |= n;
            u3c |= cb; u3p |= pb; u3n |= nb;
            if (dr >= -2 && dr <= 2) {
                v2c |= c;  v2p |= p;  v2n |= n;
                u2c |= cb; u2p |= pb; u2n |= nb;
            }
            if (dr >= -1 && dr <= 1) {
                v1c |= c;  v1p |= p;  v1n |= n;
                u1c |= cb; u1p |= pb; u1n |= nb;
            }
        }
        const uint32_t d1f = v1c | (v1c << 1) | (v1p >> 31) | (v1c >> 1) | (v1n << 31);
        const uint32_t d2f = v2c | (v2c << 1) | (v2p >> 31) | (v2c >> 1) | (v2n << 31)
                                 | (v2c << 2) | (v2p >> 30) | (v2c >> 2) | (v2n << 30);
        const uint32_t d3f = v3c | (v3c << 1) | (v3p >> 31) | (v3c >> 1) | (v3n << 31)
                                 | (v3c << 2) | (v3p >> 30) | (v3c >> 2) | (v3n << 30)
                                 | (v3c << 3) | (v3p >> 29) | (v3c >> 3) | (v3n << 29);
        const uint32_t d1b = u1c | (u1c << 1) | (u1p >> 31) | (u1c >> 1) | (u1n << 31);
        const uint32_t d2b = u2c | (u2c << 1) | (u2p >> 31) | (u2c >> 1) | (u2n << 31)
                                 | (u2c << 2) | (u2p >> 30) | (u2c >> 2) | (u2n << 30);
        const uint32_t d3b = u3c | (u3c << 1) | (u3p >> 31) | (u3c >> 1) | (u3n << 31)
                                 | (u3c << 2) | (u3p >> 30) | (u3c >> 2) | (u3n << 30)
                                 | (u3c << 3) | (u3p >> 29) | (u3c >> 3) | (u3n << 29);
        uint4 pl;
        pl.x = tw;                                  // target bits
        pl.y = (tw & d1b) | (~tw & d1f);            // dist<=1 to opposite class
        pl.z = (tw & d2b) | (~tw & d2f);            // dist<=2
        pl.w = (tw & d3b) | (~tw & d3f);            // dist<=3  (nested)
        plane[row][wz] = pl;
        ct += __popc(pl.x);
        c1 += __popc(pl.y);
        c2 += __popc(pl.z);
        c3 += __popc(pl.w);
    }
    __syncthreads();

    // ---- phase C: per-pixel math, packed-f32 pairs; depth-2 global prefetch
    v2f a_pt = {0.f, 0.f}, a_p = {0.f, 0.f}, a_bw = {0.f, 0.f},
        a_ce = {0.f, 0.f}, a_f = {0.f, 0.f};
    const int wz = tid >> 3;             // word index for cols tid*4..tid*4+3
    const int sh = (tid & 7) << 2;       // bit offset of col tid*4 within the word

    const v2f dW12 = {W1 - W2, W1 - W2};
    const v2f dW23 = {W2 - W3, W2 - W3};
    const v2f cW3  = {W3, W3};
    const v2f kM2  = {-2.f, -2.f};
    const v2f kP1  = {1.f, 1.f};
    const v2f kMH  = {-0.5f, -0.5f};
    const v2f k34  = {0.75f, 0.75f};

    for (int rr = 0; rr < TR; ++rr) {
        const float4 cur = xa;
        xa = xb;
        if (rr + 2 < TR) xb = p4[(rr + 2) * 256 + tid];
        const uint4 pl = plane[rr][wz];  // broadcast b128 read, conflict-free
#pragma unroll
        for (int h = 0; h < 2; ++h) {    // pixel pair (2h, 2h+1)
            v2f x;
            x.x = (h == 0) ? cur.x : cur.z;
            x.y = (h == 0) ? cur.y : cur.w;
            const int q0 = sh + (h << 1);

            v2f tf = {(float)((pl.x >> q0) & 1u), (float)((pl.x >> (q0 + 1)) & 1u)};
            v2f f1 = {(float)((pl.y >> q0) & 1u), (float)((pl.y >> (q0 + 1)) & 1u)};
            v2f f2 = {(float)((pl.z >> q0) & 1u), (float)((pl.z >> (q0 + 1)) & 1u)};
            v2f f3 = {(float)((pl.w >> q0) & 1u), (float)((pl.w >> (q0 + 1)) & 1u)};

            // e = exp(-|x|); abs+neg fold into the scale-mul's operand modifiers
            v2f ea;
            ea.x = fabsf(x.x) * -1.4426950408889634f;
            ea.y = fabsf(x.y) * -1.4426950408889634f;
            v2f e   = {__builtin_amdgcn_exp2f(ea.x), __builtin_amdgcn_exp2f(ea.y)};
            v2f opl = e + 1.0f;
            v2f inv = {__builtin_amdgcn_rcpf(opl.x), __builtin_amdgcn_rcpf(opl.y)};
            v2f lg  = {__builtin_amdgcn_logf(opl.x), __builtin_amdgcn_logf(opl.y)};
            v2f l1p = lg * 0.6931471805599453f;      // log1p(exp(-|x|))
            v2f pm  = 1.0f - inv;
            v2f p;                                   // sigmoid(x)
            p.x = (x.x >= 0.f) ? inv.x : pm.x;
            p.y = (x.y >= 0.f) ? inv.y : pm.y;

            v2f mx;
            mx.x = fmaxf(x.x, 0.f);
            mx.y = fmaxf(x.y, 0.f);
            v2f ce  = pk_fma(x, -tf, mx + l1p);      // stable BCE-with-logits

            v2f m2p = pk_fma(p, kM2, kP1);
            v2f omp = pk_fma(tf, m2p, p);            // 1 - p_t
            v2f at  = pk_fma(tf, kMH, k34);
            v2f o2  = omp * omp;
            a_f  = pk_fma(o2 * at, ce, a_f);         // focal

            v2f w = pk_fma(f1, dW12, pk_fma(f2, dW23, f3 * cW3));
            a_bw = pk_fma(w, ce, a_bw);
            a_ce += ce;
            a_p  += p;
            a_pt  = pk_fma(tf, p, a_pt);
        }
    }

    // combine packed lanes + popcount-derived sums; deterministic reduction
    float v[7];
    v[0] = a_pt.x + a_pt.y;
    v[1] = a_p.x + a_p.y;
    v[2] = (float)ct;                                   // sum(t)
    v[3] = fmaf((float)c1, W1 - W2,
           fmaf((float)c2, W2 - W3, (float)c3 * W3));   // sum(w)
    v[4] = a_bw.x + a_bw.y;
    v[5] = a_ce.x + a_ce.y;
    v[6] = a_f.x + a_f.y;
#pragma unroll
    for (int off = 1; off < 64; off <<= 1) {
#pragma unroll
        for (int j = 0; j < 7; ++j) v[j] += __shfl_xor(v[j], off);
    }
    if (lane == 0) {
#pragma unroll
        for (int j = 0; j < 7; ++j) red[wid][j] = v[j];
    }
    __syncthreads();
    if (tid < 7) {
        float s = red[0][tid] + red[1][tid] + red[2][tid] + red[3][tid];
        ws[tid * NBLK + blk] = s;
    }
}

// merged per-batch reduction + final scalar math (one launch)
__global__ __launch_bounds__(256) void k_tail(const float* __restrict__ ws,
                                              const float* __restrict__ lv,
                                              float* __restrict__ out) {
    __shared__ float res[7][BATCH];
    const int tid = threadIdx.x;
    const int b   = tid >> 3;          // batch 0..31
    const int g   = tid & 7;           // 8 threads per batch
#pragma unroll
    for (int q = 0; q < 7; ++q) {
        float s = 0.f;
#pragma unroll
        for (int i = 0; i < TILES / 8; ++i) s += ws[q * NBLK + b * TILES + g + i * 8];
        s += __shfl_xor(s, 1);
        s += __shfl_xor(s, 2);
        s += __shfl_xor(s, 4);
        if (g == 0) res[q][b] = s;
    }
    __syncthreads();
    if (tid < 32) {
        const float pt = res[0][tid];
        const float p  = res[1][tid];
        const float t  = res[2][tid];
        const float w  = res[3][tid];
        const float bw = res[4][tid];
        float d  = 1.f - (2.f * pt + 1.f) / (p + t + 1.f);
        float io = 1.f - (pt + 1e-6f) / (p + t - pt + 1e-6f);
        float bn = bw / fmaxf(w, 1.f);
        float ce = res[5][tid];
        float fo = res[6][tid];
#pragma unroll
        for (int off = 1; off < 32; off <<= 1) {
            d  += __shfl_xor(d, off);
            io += __shfl_xor(io, off);
            bn += __shfl_xor(bn, off);
            ce += __shfl_xor(ce, off);
            fo += __shfl_xor(fo, off);
        }
        if (tid == 0) {
            const float N = 33554432.f;   // 32*1024*1024
            float ls[5];
            ls[0] = ce / N;                        // ce
            ls[1] = d * (1.f / 32.f);              // dice
            ls[2] = 0.5f * fo / N;                 // focal
            ls[3] = 0.3f * io * (1.f / 32.f);      // iou
            ls[4] = 0.2f * bn * (1.f / 32.f);      // boundary
            float r[5], s = 0.f;
#pragma unroll
            for (int i = 0; i < 5; ++i) {
                r[i] = 1.f / (1.f + __expf(-lv[i] * (1.f / 1.5f)));
                s += r[i];
            }
            float tot = 0.f;
#pragma unroll
            for (int i = 0; i < 5; ++i) tot += (r[i] / s) * 5.f * ls[i];
            out[0] = tot;
        }
    }
}

extern "C" void kernel_launch(void* const* d_in, const int* in_sizes, int n_in,
                              void* d_out, int out_size, void* d_ws, size_t ws_size,
                              hipStream_t stream) {
    const float* pred = (const float*)d_in[0];
    const float* targ = (const float*)d_in[1];
    const float* lv   = (const float*)d_in[2];
    float* out = (float*)d_out;
    float* ws  = (float*)d_ws;                 // [7][NBLK] partials

    k_main<<<NBLK, 256, 0, stream>>>(pred, targ, ws);
    k_tail<<<1, 256, 0, stream>>>(ws, lv, out);
}